// Round 1
// baseline (385.884 us; speedup 1.0000x reference)
//
#include <hip/hip_runtime.h>
#include <type_traits>

#define B_    2
#define N_    2048
#define EMBED 896
#define HQ    16
#define HK    4
#define D_    56
#define DP    64
#define G_    4

typedef unsigned short u16;
typedef unsigned int   u32;
typedef __attribute__((ext_vector_type(8))) short bf16x8;
typedef __attribute__((ext_vector_type(4))) float f32x4;

__device__ __forceinline__ u16 f2bf(float f) {
  u32 u = __builtin_bit_cast(u32, f);
  return (u16)((u + 0x7FFFu + ((u >> 16) & 1u)) >> 16);
}

// ---------------------------------------------------------------------------
// C[M x N] = A[M x K] (f32, row-major) * B[N x K]^T (f32, row-major)
// bf16 MFMA with f32 accumulate. BM=BN=128, BK=64, 256 threads (4 waves, 2x2).
// ---------------------------------------------------------------------------
template <typename OUT_T>
__global__ __launch_bounds__(256) void gemm_bt(const float* __restrict__ A,
                                               const float* __restrict__ Bw,
                                               OUT_T* __restrict__ C,
                                               int M, int N, int K) {
  __shared__ __align__(16) u16 As[128][72];
  __shared__ __align__(16) u16 Bs[128][72];
  const int t = threadIdx.x;
  const int m0 = blockIdx.x * 128;
  const int n0 = blockIdx.y * 128;
  const int w = t >> 6, lane = t & 63;
  const int wr = (w >> 1) * 64, wc = (w & 1) * 64;
  const int fr = lane & 15, fg = lane >> 4;

  f32x4 acc[4][4] = {};

  for (int k0 = 0; k0 < K; k0 += 64) {
#pragma unroll
    for (int i = 0; i < 8; i++) {
      int flat = t + 256 * i;       // 0..2047
      int r = flat >> 4;            // 0..127
      int c = (flat & 15) * 4;      // 0..60
      float4 va = *(const float4*)(A + (size_t)(m0 + r) * K + k0 + c);
      uint2 pa;
      pa.x = (u32)f2bf(va.x) | ((u32)f2bf(va.y) << 16);
      pa.y = (u32)f2bf(va.z) | ((u32)f2bf(va.w) << 16);
      *(uint2*)&As[r][c] = pa;
      float4 vb = make_float4(0.f, 0.f, 0.f, 0.f);
      if (n0 + r < N) vb = *(const float4*)(Bw + (size_t)(n0 + r) * K + k0 + c);
      uint2 pb;
      pb.x = (u32)f2bf(vb.x) | ((u32)f2bf(vb.y) << 16);
      pb.y = (u32)f2bf(vb.z) | ((u32)f2bf(vb.w) << 16);
      *(uint2*)&Bs[r][c] = pb;
    }
    __syncthreads();
#pragma unroll
    for (int kk = 0; kk < 64; kk += 32) {
      bf16x8 af[4], bfv[4];
#pragma unroll
      for (int mf = 0; mf < 4; mf++)
        af[mf] = *(const bf16x8*)&As[wr + mf * 16 + fr][kk + fg * 8];
#pragma unroll
      for (int nf = 0; nf < 4; nf++)
        bfv[nf] = *(const bf16x8*)&Bs[wc + nf * 16 + fr][kk + fg * 8];
#pragma unroll
      for (int mf = 0; mf < 4; mf++)
#pragma unroll
        for (int nf = 0; nf < 4; nf++)
          acc[mf][nf] = __builtin_amdgcn_mfma_f32_16x16x32_bf16(
              af[mf], bfv[nf], acc[mf][nf], 0, 0, 0);
    }
    __syncthreads();
  }

#pragma unroll
  for (int mf = 0; mf < 4; mf++) {
#pragma unroll
    for (int nf = 0; nf < 4; nf++) {
      int col = n0 + wc + nf * 16 + fr;
      if (col < N) {
#pragma unroll
        for (int r = 0; r < 4; r++) {
          int row = m0 + wr + mf * 16 + fg * 4 + r;
          float v = acc[mf][nf][r];
          if constexpr (std::is_same<OUT_T, u16>::value)
            C[(size_t)row * N + col] = f2bf(v);
          else
            C[(size_t)row * N + col] = v;
        }
      }
    }
  }
}

// ---------------------------------------------------------------------------
// Repack projection outputs into head-padded layouts (pad D=56 -> 64 w/ zeros)
// ---------------------------------------------------------------------------
__global__ __launch_bounds__(256) void repack_q(const u16* __restrict__ Cq,
                                                u16* __restrict__ Qp) {
  int tid = blockIdx.x * 256 + threadIdx.x;  // 2*16*2048*64 = 2^22
  int d = tid & 63;
  int i = (tid >> 6) & 2047;
  int h = (tid >> 17) & 15;
  int b = tid >> 21;
  u16 v = 0;
  if (d < D_) v = Cq[((size_t)(b * N_ + i)) * EMBED + h * D_ + d];
  Qp[tid] = v;
}

__global__ __launch_bounds__(256) void repack_k(const u16* __restrict__ Ck,
                                                u16* __restrict__ Kp) {
  int tid = blockIdx.x * 256 + threadIdx.x;  // 2*4*2048*64 = 2^20
  int d = tid & 63;
  int i = (tid >> 6) & 2047;
  int hk = (tid >> 17) & 3;
  int b = tid >> 19;
  u16 v = 0;
  if (d < D_) v = Ck[((size_t)(b * N_ + i)) * (HK * D_) + hk * D_ + d];
  Kp[tid] = v;
}

__global__ __launch_bounds__(256) void repack_v(const u16* __restrict__ Cv,
                                                u16* __restrict__ Vt) {
  int tid = blockIdx.x * 256 + threadIdx.x;  // 2^20 ; layout ((b*4+hk)*64+d)*2048+s
  int s = tid & 2047;
  int d = (tid >> 11) & 63;
  int hk = (tid >> 17) & 3;
  int b = tid >> 19;
  u16 v = 0;
  if (d < D_) v = Cv[((size_t)(b * N_ + s)) * (HK * D_) + hk * D_ + d];
  Vt[tid] = v;
}

// ---------------------------------------------------------------------------
// Pass A: causal flash attention (no-max-subtraction softmax), writes
// normalized O scattered into (b, n, EMBED) f32 and 1/l per row.
// Block = 256 thr (4 waves); block owns 64 q-rows of one (b, h).
// ---------------------------------------------------------------------------
__global__ __launch_bounds__(256) void attn_fwd(const u16* __restrict__ Qp,
                                                const u16* __restrict__ Kp,
                                                const u16* __restrict__ Vt,
                                                float* __restrict__ AO,
                                                float* __restrict__ linv_g) {
  const int qt = blockIdx.x, h = blockIdx.y, b = blockIdx.z;
  const int hk = h >> 2;
  __shared__ __align__(16) u16 Qs[64][72];
  __shared__ __align__(16) u16 Ks[64][72];
  __shared__ __align__(16) u16 Vs[64][72];  // [d][s_local]
  __shared__ __align__(16) u16 Ps[64][72];
  const int t = threadIdx.x, w = t >> 6, lane = t & 63;
  const int fr = lane & 15, fg = lane >> 4;
  const float rscale = 0.13363062095621219f;  // 1/sqrt(56)

  const u16* Qbase = Qp + ((size_t)(b * HQ + h) * N_ + qt * 64) * DP;
#pragma unroll
  for (int i = 0; i < 2; i++) {
    int flat = t + 256 * i;
    int r = flat >> 3, c = (flat & 7) * 8;
    *(int4*)&Qs[r][c] = *(const int4*)(Qbase + r * DP + c);
  }

  float l_acc[4] = {0.f, 0.f, 0.f, 0.f};
  f32x4 oacc[4] = {};
  __syncthreads();

  for (int kt = 0; kt <= qt; kt++) {
    const u16* Kbase = Kp + ((size_t)(b * HK + hk) * N_ + kt * 64) * DP;
    const u16* Vbase = Vt + (size_t)(b * HK + hk) * DP * N_ + kt * 64;
#pragma unroll
    for (int i = 0; i < 2; i++) {
      int flat = t + 256 * i;
      int r = flat >> 3, c = (flat & 7) * 8;
      *(int4*)&Ks[r][c] = *(const int4*)(Kbase + r * DP + c);
      *(int4*)&Vs[r][c] = *(const int4*)(Vbase + (size_t)r * N_ + c);
    }
    __syncthreads();

    // S = Q * K^T for this wave's 16 rows x 64 cols
    f32x4 sf[4] = {};
#pragma unroll
    for (int kk = 0; kk < 64; kk += 32) {
      bf16x8 aq = *(const bf16x8*)&Qs[w * 16 + fr][kk + fg * 8];
#pragma unroll
      for (int jf = 0; jf < 4; jf++) {
        bf16x8 bk = *(const bf16x8*)&Ks[jf * 16 + fr][kk + fg * 8];
        sf[jf] = __builtin_amdgcn_mfma_f32_16x16x32_bf16(aq, bk, sf[jf], 0, 0, 0);
      }
    }
    const int gi_base = qt * 64 + w * 16 + fg * 4;
#pragma unroll
    for (int jf = 0; jf < 4; jf++) {
      int gj = kt * 64 + jf * 16 + fr;
#pragma unroll
      for (int r = 0; r < 4; r++) {
        float p = (gj <= gi_base + r) ? __expf(sf[jf][r] * rscale) : 0.f;
        l_acc[r] += p;  // lane-partial; cross-lane reduce at end
        Ps[w * 16 + fg * 4 + r][jf * 16 + fr] = f2bf(p);
      }
    }
    __syncthreads();

    // O += P * V (Vs rows are d, cols are s_local)
#pragma unroll
    for (int kk = 0; kk < 64; kk += 32) {
      bf16x8 ap = *(const bf16x8*)&Ps[w * 16 + fr][kk + fg * 8];
#pragma unroll
      for (int df = 0; df < 4; df++) {
        bf16x8 bv = *(const bf16x8*)&Vs[df * 16 + fr][kk + fg * 8];
        oacc[df] = __builtin_amdgcn_mfma_f32_16x16x32_bf16(ap, bv, oacc[df], 0, 0, 0);
      }
    }
    __syncthreads();
  }

#pragma unroll
  for (int r = 0; r < 4; r++) {
    float v = l_acc[r];
    v += __shfl_xor(v, 1);
    v += __shfl_xor(v, 2);
    v += __shfl_xor(v, 4);
    v += __shfl_xor(v, 8);
    l_acc[r] = 1.0f / v;
  }
  const int gi_base = qt * 64 + w * 16 + fg * 4;
#pragma unroll
  for (int df = 0; df < 4; df++) {
    int d = df * 16 + fr;
    if (d < D_) {
#pragma unroll
      for (int r = 0; r < 4; r++)
        AO[((size_t)b * N_ + gi_base + r) * EMBED + h * D_ + d] =
            oacc[df][r] * l_acc[r];
    }
  }
  if (fr == 0) {
#pragma unroll
    for (int r = 0; r < 4; r++)
      linv_g[((size_t)b * HQ + h) * N_ + gi_base + r] = l_acc[r];
  }
}

// ---------------------------------------------------------------------------
// Pass B: attention-weight column means. Computes T = K*Q^T (transposed
// scores) so per-column sums become row sums; uses 1/l from pass A.
// aw[b][j][h] = (1/N) * sum_i exp(s_ij)/l_i  for i >= j
// ---------------------------------------------------------------------------
__global__ __launch_bounds__(256) void attn_aw(const u16* __restrict__ Qp,
                                               const u16* __restrict__ Kp,
                                               const float* __restrict__ linv_g,
                                               float* __restrict__ aw) {
  const int ct = blockIdx.x, h = blockIdx.y, b = blockIdx.z;
  const int hk = h >> 2;
  __shared__ __align__(16) u16 Ks[64][72];
  __shared__ __align__(16) u16 Qs[64][72];
  const int t = threadIdx.x, w = t >> 6, lane = t & 63;
  const int fr = lane & 15, fg = lane >> 4;
  const float rscale = 0.13363062095621219f;

  const u16* Kbase = Kp + ((size_t)(b * HK + hk) * N_ + ct * 64) * DP;
#pragma unroll
  for (int i = 0; i < 2; i++) {
    int flat = t + 256 * i;
    int r = flat >> 3, c = (flat & 7) * 8;
    *(int4*)&Ks[r][c] = *(const int4*)(Kbase + r * DP + c);
  }
  float s_acc[4] = {0.f, 0.f, 0.f, 0.f};
  const float* linv_h = linv_g + ((size_t)b * HQ + h) * N_;
  __syncthreads();

  for (int rt = ct; rt < N_ / 64; rt++) {
    const u16* Qbase = Qp + ((size_t)(b * HQ + h) * N_ + rt * 64) * DP;
#pragma unroll
    for (int i = 0; i < 2; i++) {
      int flat = t + 256 * i;
      int r = flat >> 3, c = (flat & 7) * 8;
      *(int4*)&Qs[r][c] = *(const int4*)(Qbase + r * DP + c);
    }
    __syncthreads();
    f32x4 tac[4] = {};
#pragma unroll
    for (int kk = 0; kk < 64; kk += 32) {
      bf16x8 ak = *(const bf16x8*)&Ks[w * 16 + fr][kk + fg * 8];
#pragma unroll
      for (int ifr = 0; ifr < 4; ifr++) {
        bf16x8 bq = *(const bf16x8*)&Qs[ifr * 16 + fr][kk + fg * 8];
        tac[ifr] = __builtin_amdgcn_mfma_f32_16x16x32_bf16(ak, bq, tac[ifr], 0, 0, 0);
      }
    }
    const int gj_base = ct * 64 + w * 16 + fg * 4;
#pragma unroll
    for (int ifr = 0; ifr < 4; ifr++) {
      int gi = rt * 64 + ifr * 16 + fr;
      float li = linv_h[gi];
#pragma unroll
      for (int r = 0; r < 4; r++) {
        if (gi >= gj_base + r) s_acc[r] += __expf(tac[ifr][r] * rscale) * li;
      }
    }
    __syncthreads();
  }
  const int gj_base = ct * 64 + w * 16 + fg * 4;
#pragma unroll
  for (int r = 0; r < 4; r++) {
    float v = s_acc[r];
    v += __shfl_xor(v, 1);
    v += __shfl_xor(v, 2);
    v += __shfl_xor(v, 4);
    v += __shfl_xor(v, 8);
    if (fr == 0) aw[((size_t)b * N_ + gj_base + r) * HQ + h] = v * (1.0f / N_);
  }
}

// ---------------------------------------------------------------------------
// LayerNorm over EMBED, one block per row
// ---------------------------------------------------------------------------
__global__ __launch_bounds__(256) void ln_fwd(const float* __restrict__ AO,
                                              const float* __restrict__ gamma,
                                              const float* __restrict__ beta,
                                              float* __restrict__ out) {
  const int row = blockIdx.x;
  const float* x = AO + (size_t)row * EMBED;
  const int t = threadIdx.x;
  float s = 0.f, s2 = 0.f;
  float v[4];
#pragma unroll
  for (int i = 0; i < 4; i++) {
    int c = t + 256 * i;
    v[i] = (c < EMBED) ? x[c] : 0.f;
    s += v[i];
    s2 += v[i] * v[i];
  }
#pragma unroll
  for (int m = 1; m <= 32; m <<= 1) {
    s += __shfl_xor(s, m);
    s2 += __shfl_xor(s2, m);
  }
  __shared__ float red[8];
  const int w = t >> 6, lane = t & 63;
  if (lane == 0) {
    red[w] = s;
    red[4 + w] = s2;
  }
  __syncthreads();
  s = red[0] + red[1] + red[2] + red[3];
  s2 = red[4] + red[5] + red[6] + red[7];
  const float mu = s * (1.0f / EMBED);
  const float var = s2 * (1.0f / EMBED) - mu * mu;
  const float rs = rsqrtf(var + 1e-5f);
#pragma unroll
  for (int i = 0; i < 4; i++) {
    int c = t + 256 * i;
    if (c < EMBED)
      out[(size_t)row * EMBED + c] = (v[i] - mu) * rs * gamma[c] + beta[c];
  }
}

// ---------------------------------------------------------------------------
extern "C" void kernel_launch(void* const* d_in, const int* in_sizes, int n_in,
                              void* d_out, int out_size, void* d_ws,
                              size_t ws_size, hipStream_t stream) {
  (void)in_sizes; (void)n_in; (void)out_size; (void)ws_size;
  const float* query = (const float*)d_in[0];
  const float* key   = (const float*)d_in[1];
  const float* value = (const float*)d_in[2];
  const float* Wq    = (const float*)d_in[3];
  const float* Wk    = (const float*)d_in[4];
  const float* Wv    = (const float*)d_in[5];
  const float* Wo    = (const float*)d_in[6];
  const float* gamma = (const float*)d_in[7];
  const float* beta  = (const float*)d_in[8];

  float* out = (float*)d_out;                   // (b, n, EMBED) f32
  float* aw  = out + (size_t)B_ * N_ * EMBED;   // (b, s, HQ)   f32

  char* ws = (char*)d_ws;
  u16* Cq = (u16*)ws;              ws += (size_t)B_ * N_ * EMBED * 2;   // 7.3 MB
  u16* Ck = (u16*)ws;              ws += (size_t)B_ * N_ * HK * D_ * 2; // 1.8 MB
  u16* Cv = (u16*)ws;              ws += (size_t)B_ * N_ * HK * D_ * 2;
  u16* Qp = (u16*)ws;              ws += (size_t)B_ * HQ * N_ * DP * 2; // 8.4 MB
  u16* Kp = (u16*)ws;              ws += (size_t)B_ * HK * N_ * DP * 2; // 2.1 MB
  u16* Vt = (u16*)ws;              ws += (size_t)B_ * HK * N_ * DP * 2;
  float* AO   = (float*)ws;        ws += (size_t)B_ * N_ * EMBED * 4;   // 14.7 MB
  float* LNo  = (float*)ws;        ws += (size_t)B_ * N_ * EMBED * 4;
  float* linv = (float*)ws;        ws += (size_t)B_ * HQ * N_ * 4;      // 0.26 MB

  dim3 blk(256);
  const int M = B_ * N_;  // 4096

  gemm_bt<u16><<<dim3(M / 128, EMBED / 128), blk, 0, stream>>>(query, Wq, Cq, M, EMBED, EMBED);
  gemm_bt<u16><<<dim3(M / 128, 2), blk, 0, stream>>>(key, Wk, Ck, M, HK * D_, EMBED);
  gemm_bt<u16><<<dim3(M / 128, 2), blk, 0, stream>>>(value, Wv, Cv, M, HK * D_, EMBED);

  repack_q<<<dim3((B_ * HQ * N_ * DP) / 256), blk, 0, stream>>>(Cq, Qp);
  repack_k<<<dim3((B_ * HK * N_ * DP) / 256), blk, 0, stream>>>(Ck, Kp);
  repack_v<<<dim3((B_ * HK * N_ * DP) / 256), blk, 0, stream>>>(Cv, Vt);

  attn_fwd<<<dim3(N_ / 64, HQ, B_), blk, 0, stream>>>(Qp, Kp, Vt, AO, linv);
  attn_aw<<<dim3(N_ / 64, HQ, B_), blk, 0, stream>>>(Qp, Kp, linv, aw);

  ln_fwd<<<dim3(M), blk, 0, stream>>>(AO, gamma, beta, LNo);
  gemm_bt<float><<<dim3(M / 128, EMBED / 128), blk, 0, stream>>>(LNo, Wo, out, M, EMBED, EMBED);
}

// Round 3
// 321.113 us; speedup vs baseline: 1.2017x; 1.2017x over previous
//
#include <hip/hip_runtime.h>
#include <type_traits>

#define B_    2
#define N_    2048
#define EMBED 896
#define HQ    16
#define HK    4
#define D_    56
#define DP    64

typedef unsigned short u16;
typedef unsigned int   u32;
typedef __attribute__((ext_vector_type(8))) short bf16x8;
typedef __attribute__((ext_vector_type(4))) float f32x4;

__device__ __forceinline__ u16 f2bf(float f) {
  u32 u = __builtin_bit_cast(u32, f);
  return (u16)((u + 0x7FFFu + ((u >> 16) & 1u)) >> 16);
}

#define EXP2F(x) __builtin_amdgcn_exp2f(x)

// QSCALE = (1/sqrt(56)) * log2(e); folded into Q so softmax uses exp2
#define QSCALE 0.19278822f

// ---------------------------------------------------------------------------
// C[M x N] = A[M x K] * B[N x K]^T.  A: f32 (convert) or bf16 (direct).
// MODE 0: plain f32 C.  MODE 1/2/3: bf16 scatter to Qp / Kp / Vt layouts.
// ---------------------------------------------------------------------------
template <typename AT, int MODE>
__global__ __launch_bounds__(256) void gemm_bt(const AT* __restrict__ A,
                                               const float* __restrict__ Bw,
                                               void* __restrict__ Cout,
                                               int M, int N, int K) {
  __shared__ __align__(16) u16 As[128][72];
  __shared__ __align__(16) u16 Bs[128][72];
  const int t = threadIdx.x;
  const int m0 = blockIdx.x * 128;
  const int n0 = blockIdx.y * 128;
  const int w = t >> 6, lane = t & 63;
  const int wr = (w >> 1) * 64, wc = (w & 1) * 64;
  const int fr = lane & 15, fg = lane >> 4;

  f32x4 acc[4][4] = {};

  for (int k0 = 0; k0 < K; k0 += 64) {
    if constexpr (std::is_same<AT, float>::value) {
#pragma unroll
      for (int i = 0; i < 8; i++) {
        int flat = t + 256 * i;
        int r = flat >> 4, c = (flat & 15) * 4;
        float4 va = *(const float4*)(A + (size_t)(m0 + r) * K + k0 + c);
        uint2 pa;
        pa.x = (u32)f2bf(va.x) | ((u32)f2bf(va.y) << 16);
        pa.y = (u32)f2bf(va.z) | ((u32)f2bf(va.w) << 16);
        *(uint2*)&As[r][c] = pa;
      }
    } else {
#pragma unroll
      for (int i = 0; i < 4; i++) {
        int flat = t + 256 * i;
        int r = flat >> 3, c = (flat & 7) * 8;
        *(int4*)&As[r][c] = *(const int4*)(A + (size_t)(m0 + r) * K + k0 + c);
      }
    }
#pragma unroll
    for (int i = 0; i < 8; i++) {
      int flat = t + 256 * i;
      int r = flat >> 4, c = (flat & 15) * 4;
      float4 vb = make_float4(0.f, 0.f, 0.f, 0.f);
      if (n0 + r < N) vb = *(const float4*)(Bw + (size_t)(n0 + r) * K + k0 + c);
      uint2 pb;
      pb.x = (u32)f2bf(vb.x) | ((u32)f2bf(vb.y) << 16);
      pb.y = (u32)f2bf(vb.z) | ((u32)f2bf(vb.w) << 16);
      *(uint2*)&Bs[r][c] = pb;
    }
    __syncthreads();
#pragma unroll
    for (int kk = 0; kk < 64; kk += 32) {
      bf16x8 af[4], bfv[4];
#pragma unroll
      for (int mf = 0; mf < 4; mf++)
        af[mf] = *(const bf16x8*)&As[wr + mf * 16 + fr][kk + fg * 8];
#pragma unroll
      for (int nf = 0; nf < 4; nf++)
        bfv[nf] = *(const bf16x8*)&Bs[wc + nf * 16 + fr][kk + fg * 8];
#pragma unroll
      for (int mf = 0; mf < 4; mf++)
#pragma unroll
        for (int nf = 0; nf < 4; nf++)
          acc[mf][nf] = __builtin_amdgcn_mfma_f32_16x16x32_bf16(
              af[mf], bfv[nf], acc[mf][nf], 0, 0, 0);
    }
    __syncthreads();
  }

#pragma unroll
  for (int mf = 0; mf < 4; mf++) {
#pragma unroll
    for (int nf = 0; nf < 4; nf++) {
      int col = n0 + wc + nf * 16 + fr;
      if (col < N) {
        if constexpr (MODE == 0) {
          float* C = (float*)Cout;
#pragma unroll
          for (int r = 0; r < 4; r++) {
            int row = m0 + wr + mf * 16 + fg * 4 + r;
            C[(size_t)row * N + col] = acc[mf][nf][r];
          }
        } else {
          u16* O = (u16*)Cout;
          int hh = col / 56, d = col - hh * 56;
#pragma unroll
          for (int r = 0; r < 4; r++) {
            int row = m0 + wr + mf * 16 + fg * 4 + r;
            int bb = row >> 11, nn = row & 2047;
            float v = acc[mf][nf][r];
            size_t addr = 0;
            if constexpr (MODE == 1) {
              addr = ((size_t)((bb * 16 + hh) * 2048 + nn)) * 64 + d;
              v *= QSCALE;
            }
            if constexpr (MODE == 2)
              addr = ((size_t)((bb * 4 + hh) * 2048 + nn)) * 64 + d;
            if constexpr (MODE == 3)
              addr = ((size_t)((bb * 4 + hh) * 64 + d)) * 2048 + nn;
            O[addr] = f2bf(v);
          }
        }
      }
    }
  }
}

// ---------------------------------------------------------------------------
// Pass A: causal flash attention. Block = (strip-pair, hk, b); 4 waves, one
// head per wave sharing K/V LDS staging. 32-row q strips paired (s, 63-s)
// -> every block runs exactly 33 kv tiles. P is wave-private LDS (no barrier).
// K/V double-buffered through registers.
// ---------------------------------------------------------------------------
__global__ __launch_bounds__(256) void attn_fwd(const u16* __restrict__ Qp,
                                                const u16* __restrict__ Kp,
                                                const u16* __restrict__ Vt,
                                                float* __restrict__ AO,
                                                float* __restrict__ linv_g) {
  const int p = blockIdx.x, hk = blockIdx.y, b = blockIdx.z;
  const int t = threadIdx.x, w = t >> 6, lane = t & 63;
  const int fr = lane & 15, fg = lane >> 4;
  const int h = hk * 4 + w;

  __shared__ __align__(16) u16 Ks[64][72];
  __shared__ __align__(16) u16 Vs[64][72];
  __shared__ __align__(16) u16 Ps[4][32][72];

  const u16* Qh = Qp + (size_t)(b * HQ + h) * N_ * DP;
  const u16* Kh = Kp + (size_t)(b * HK + hk) * N_ * DP;
  const u16* Vh = Vt + (size_t)(b * HK + hk) * DP * N_;
  float* linv_h = linv_g + (size_t)(b * HQ + h) * N_;

  const int f0 = t * 2, f1 = t * 2 + 1;  // staging flat indices (2 x int4 each)

  for (int half = 0; half < 2; ++half) {
    const int s = half ? (63 - p) : p;
    const int nt = (s >> 1) + 1;

    // Q fragments in registers
    bf16x8 qf[2][2];
#pragma unroll
    for (int m = 0; m < 2; m++)
#pragma unroll
      for (int kk = 0; kk < 2; kk++)
        qf[m][kk] = *(const bf16x8*)(Qh + (size_t)(s * 32 + m * 16 + fr) * DP +
                                     kk * 32 + fg * 8);

    f32x4 oacc[2][4] = {};
    float l_acc[2][4] = {};

    // prefetch tile 0
    int4 kr0, kr1, vr0, vr1;
    {
      const u16* Kb = Kh;  // tile 0
      kr0 = *(const int4*)(Kb + f0 * 8);
      kr1 = *(const int4*)(Kb + f1 * 8);
      vr0 = *(const int4*)(Vh + (size_t)(f0 >> 3) * N_ + (f0 & 7) * 8);
      vr1 = *(const int4*)(Vh + (size_t)(f1 >> 3) * N_ + (f1 & 7) * 8);
    }

    for (int tt = 0; tt < nt; ++tt) {
      __syncthreads();  // all waves done reading previous K/V
      *(int4*)&Ks[f0 >> 3][(f0 & 7) * 8] = kr0;
      *(int4*)&Ks[f1 >> 3][(f1 & 7) * 8] = kr1;
      *(int4*)&Vs[f0 >> 3][(f0 & 7) * 8] = vr0;
      *(int4*)&Vs[f1 >> 3][(f1 & 7) * 8] = vr1;
      __syncthreads();
      if (tt + 1 < nt) {
        const u16* Kb = Kh + (size_t)(tt + 1) * 64 * DP;
        kr0 = *(const int4*)(Kb + f0 * 8);
        kr1 = *(const int4*)(Kb + f1 * 8);
        const u16* Vb = Vh + (tt + 1) * 64;
        vr0 = *(const int4*)(Vb + (size_t)(f0 >> 3) * N_ + (f0 & 7) * 8);
        vr1 = *(const int4*)(Vb + (size_t)(f1 >> 3) * N_ + (f1 & 7) * 8);
      }

      // QK^T
      f32x4 sacc[2][4] = {};
#pragma unroll
      for (int kk = 0; kk < 2; kk++) {
        bf16x8 bk[4];
#pragma unroll
        for (int jf = 0; jf < 4; jf++)
          bk[jf] = *(const bf16x8*)&Ks[jf * 16 + fr][kk * 32 + fg * 8];
#pragma unroll
        for (int m = 0; m < 2; m++)
#pragma unroll
          for (int jf = 0; jf < 4; jf++)
            sacc[m][jf] = __builtin_amdgcn_mfma_f32_16x16x32_bf16(
                qf[m][kk], bk[jf], sacc[m][jf], 0, 0, 0);
      }

      // exp2 + P store (wave-private LDS region -> no barrier)
      if (tt == nt - 1) {
#pragma unroll
        for (int m = 0; m < 2; m++)
#pragma unroll
          for (int jf = 0; jf < 4; jf++)
#pragma unroll
            for (int r = 0; r < 4; r++) {
              int gi = s * 32 + m * 16 + fg * 4 + r;
              int gj = tt * 64 + jf * 16 + fr;
              float pv = (gj <= gi) ? EXP2F(sacc[m][jf][r]) : 0.f;
              l_acc[m][r] += pv;
              Ps[w][m * 16 + fg * 4 + r][jf * 16 + fr] = f2bf(pv);
            }
      } else {
#pragma unroll
        for (int m = 0; m < 2; m++)
#pragma unroll
          for (int jf = 0; jf < 4; jf++)
#pragma unroll
            for (int r = 0; r < 4; r++) {
              float pv = EXP2F(sacc[m][jf][r]);
              l_acc[m][r] += pv;
              Ps[w][m * 16 + fg * 4 + r][jf * 16 + fr] = f2bf(pv);
            }
      }

      // P @ V  (Vs rows are d, cols are s_local)
#pragma unroll
      for (int kk = 0; kk < 2; kk++) {
        bf16x8 ap[2], bv[4];
#pragma unroll
        for (int m = 0; m < 2; m++)
          ap[m] = *(const bf16x8*)&Ps[w][m * 16 + fr][kk * 32 + fg * 8];
#pragma unroll
        for (int df = 0; df < 4; df++)
          bv[df] = *(const bf16x8*)&Vs[df * 16 + fr][kk * 32 + fg * 8];
#pragma unroll
        for (int m = 0; m < 2; m++)
#pragma unroll
          for (int df = 0; df < 4; df++)
            oacc[m][df] = __builtin_amdgcn_mfma_f32_16x16x32_bf16(
                ap[m], bv[df], oacc[m][df], 0, 0, 0);
      }
    }

    // epilogue for this strip
#pragma unroll
    for (int m = 0; m < 2; m++)
#pragma unroll
      for (int r = 0; r < 4; r++) {
        float v = l_acc[m][r];
        v += __shfl_xor(v, 1);
        v += __shfl_xor(v, 2);
        v += __shfl_xor(v, 4);
        v += __shfl_xor(v, 8);
        l_acc[m][r] = 1.0f / v;
      }
#pragma unroll
    for (int m = 0; m < 2; m++)
#pragma unroll
      for (int df = 0; df < 4; df++) {
        int d = df * 16 + fr;
        if (d < D_) {
#pragma unroll
          for (int r = 0; r < 4; r++) {
            int gi = s * 32 + m * 16 + fg * 4 + r;
            AO[((size_t)b * N_ + gi) * EMBED + h * D_ + d] =
                oacc[m][df][r] * l_acc[m][r];
          }
        }
      }
    if (fr == 0) {
#pragma unroll
      for (int m = 0; m < 2; m++)
#pragma unroll
        for (int r = 0; r < 4; r++)
          linv_h[s * 32 + m * 16 + fg * 4 + r] = l_acc[m][r];
    }
  }
}

// ---------------------------------------------------------------------------
// Pass B: attention-weight column means via transposed scores T = K*Q^T.
// Block = (col-strip-pair, hk, b); wave = head. K frags in registers; Q and
// 1/l streamed from global with 2-deep register prefetch. No LDS, no barriers.
// ---------------------------------------------------------------------------
struct QTile {
  bf16x8 q[4][2];
  float li[4];
};

#define LOADQ(dst, rt_)                                                        \
  {                                                                            \
    _Pragma("unroll") for (int ifr = 0; ifr < 4; ifr++) {                      \
      _Pragma("unroll") for (int kk = 0; kk < 2; kk++)                         \
          dst.q[ifr][kk] = *(const bf16x8*)(Qh +                               \
              (size_t)((rt_)*64 + ifr * 16 + fr) * DP + kk * 32 + fg * 8);     \
      dst.li[ifr] = linv_h[(rt_)*64 + ifr * 16 + fr];                          \
    }                                                                          \
  }

#define COMPUTET(src, rt_)                                                     \
  {                                                                            \
    f32x4 tacc[2][4] = {};                                                     \
    _Pragma("unroll") for (int kk = 0; kk < 2; kk++)                           \
        _Pragma("unroll") for (int jm = 0; jm < 2; jm++)                       \
        _Pragma("unroll") for (int ifr = 0; ifr < 4; ifr++)                    \
            tacc[jm][ifr] = __builtin_amdgcn_mfma_f32_16x16x32_bf16(           \
                kf[jm][kk], src.q[ifr][kk], tacc[jm][ifr], 0, 0, 0);           \
    if ((rt_) == rt0) {                                                        \
      _Pragma("unroll") for (int jm = 0; jm < 2; jm++)                         \
          _Pragma("unroll") for (int ifr = 0; ifr < 4; ifr++)                  \
          _Pragma("unroll") for (int r = 0; r < 4; r++) {                      \
        int gi = (rt_)*64 + ifr * 16 + fr;                                     \
        int gj = ct * 32 + jm * 16 + fg * 4 + r;                               \
        if (gi >= gj)                                                          \
          s_acc[jm][r] += EXP2F(tacc[jm][ifr][r]) * src.li[ifr];               \
      }                                                                        \
    } else {                                                                   \
      _Pragma("unroll") for (int jm = 0; jm < 2; jm++)                         \
          _Pragma("unroll") for (int ifr = 0; ifr < 4; ifr++)                  \
          _Pragma("unroll") for (int r = 0; r < 4; r++)                        \
              s_acc[jm][r] += EXP2F(tacc[jm][ifr][r]) * src.li[ifr];           \
    }                                                                          \
  }

__global__ __launch_bounds__(256) void attn_aw(const u16* __restrict__ Qp,
                                               const u16* __restrict__ Kp,
                                               const float* __restrict__ linv_g,
                                               float* __restrict__ aw) {
  const int p = blockIdx.x, hk = blockIdx.y, b = blockIdx.z;
  const int t = threadIdx.x, w = t >> 6, lane = t & 63;
  const int fr = lane & 15, fg = lane >> 4;
  const int h = hk * 4 + w;

  const u16* Qh = Qp + (size_t)(b * HQ + h) * N_ * DP;
  const u16* Kh = Kp + (size_t)(b * HK + hk) * N_ * DP;
  const float* linv_h = linv_g + (size_t)(b * HQ + h) * N_;

  for (int half = 0; half < 2; ++half) {
    const int ct = half ? (63 - p) : p;  // 32-col strip of T
    const int rt0 = ct >> 1;

    bf16x8 kf[2][2];
#pragma unroll
    for (int jm = 0; jm < 2; jm++)
#pragma unroll
      for (int kk = 0; kk < 2; kk++)
        kf[jm][kk] = *(const bf16x8*)(Kh + (size_t)(ct * 32 + jm * 16 + fr) * DP +
                                      kk * 32 + fg * 8);

    float s_acc[2][4] = {};
    QTile qa, qb;
    LOADQ(qa, rt0);
    int rt = rt0;
    while (true) {
      if (rt + 1 <= 31) LOADQ(qb, rt + 1);
      COMPUTET(qa, rt);
      rt++;
      if (rt > 31) break;
      if (rt + 1 <= 31) LOADQ(qa, rt + 1);
      COMPUTET(qb, rt);
      rt++;
      if (rt > 31) break;
    }

#pragma unroll
    for (int jm = 0; jm < 2; jm++)
#pragma unroll
      for (int r = 0; r < 4; r++) {
        float v = s_acc[jm][r];
        v += __shfl_xor(v, 1);
        v += __shfl_xor(v, 2);
        v += __shfl_xor(v, 4);
        v += __shfl_xor(v, 8);
        if (fr == 0) {
          int gj = ct * 32 + jm * 16 + fg * 4 + r;
          aw[((size_t)b * N_ + gj) * HQ + h] = v * (1.0f / N_);
        }
      }
  }
}

// ---------------------------------------------------------------------------
// LayerNorm over EMBED, one block per row; bf16 output for the Wo GEMM.
// ---------------------------------------------------------------------------
__global__ __launch_bounds__(256) void ln_fwd(const float* __restrict__ AO,
                                              const float* __restrict__ gamma,
                                              const float* __restrict__ beta,
                                              u16* __restrict__ out) {
  const int row = blockIdx.x;
  const float* x = AO + (size_t)row * EMBED;
  const int t = threadIdx.x;
  float s = 0.f, s2 = 0.f;
  float v[4];
#pragma unroll
  for (int i = 0; i < 4; i++) {
    int c = t + 256 * i;
    v[i] = (c < EMBED) ? x[c] : 0.f;
    s += v[i];
    s2 += v[i] * v[i];
  }
#pragma unroll
  for (int m = 1; m <= 32; m <<= 1) {
    s += __shfl_xor(s, m);
    s2 += __shfl_xor(s2, m);
  }
  __shared__ float red[8];
  const int w = t >> 6, lane = t & 63;
  if (lane == 0) {
    red[w] = s;
    red[4 + w] = s2;
  }
  __syncthreads();
  s = red[0] + red[1] + red[2] + red[3];
  s2 = red[4] + red[5] + red[6] + red[7];
  const float mu = s * (1.0f / EMBED);
  const float var = s2 * (1.0f / EMBED) - mu * mu;
  const float rs = rsqrtf(var + 1e-5f);
#pragma unroll
  for (int i = 0; i < 4; i++) {
    int c = t + 256 * i;
    if (c < EMBED)
      out[(size_t)row * EMBED + c] = f2bf((v[i] - mu) * rs * gamma[c] + beta[c]);
  }
}

// ---------------------------------------------------------------------------
extern "C" void kernel_launch(void* const* d_in, const int* in_sizes, int n_in,
                              void* d_out, int out_size, void* d_ws,
                              size_t ws_size, hipStream_t stream) {
  (void)in_sizes; (void)n_in; (void)out_size; (void)ws_size;
  const float* query = (const float*)d_in[0];
  const float* key   = (const float*)d_in[1];
  const float* value = (const float*)d_in[2];
  const float* Wq    = (const float*)d_in[3];
  const float* Wk    = (const float*)d_in[4];
  const float* Wv    = (const float*)d_in[5];
  const float* Wo    = (const float*)d_in[6];
  const float* gamma = (const float*)d_in[7];
  const float* beta  = (const float*)d_in[8];

  float* out = (float*)d_out;                   // (b, n, EMBED) f32
  float* aw  = out + (size_t)B_ * N_ * EMBED;   // (b, s, HQ)   f32

  char* ws = (char*)d_ws;
  u16* Qp = (u16*)ws;       ws += (size_t)B_ * HQ * N_ * DP * 2;  // 8.39 MB
  u16* Kp = (u16*)ws;       ws += (size_t)B_ * HK * N_ * DP * 2;  // 2.10 MB
  u16* Vt = (u16*)ws;       ws += (size_t)B_ * HK * N_ * DP * 2;  // 2.10 MB
  float* AO  = (float*)ws;  ws += (size_t)B_ * N_ * EMBED * 4;    // 14.7 MB
  u16* LNo   = (u16*)ws;    ws += (size_t)B_ * N_ * EMBED * 2;    // 7.34 MB
  float* linv = (float*)ws; ws += (size_t)B_ * HQ * N_ * 4;       // 0.26 MB

  const size_t pad_bytes =
      ((size_t)B_ * HQ * N_ * DP + 2 * (size_t)B_ * HK * N_ * DP) * 2;
  (void)hipMemsetAsync(Qp, 0, pad_bytes, stream);  // zero d=56..63 pads

  dim3 blk(256);
  const int M = B_ * N_;  // 4096

  gemm_bt<float, 1><<<dim3(M / 128, 7), blk, 0, stream>>>(query, Wq, Qp, M, EMBED, EMBED);
  gemm_bt<float, 2><<<dim3(M / 128, 2), blk, 0, stream>>>(key, Wk, Kp, M, HK * D_, EMBED);
  gemm_bt<float, 3><<<dim3(M / 128, 2), blk, 0, stream>>>(value, Wv, Vt, M, HK * D_, EMBED);

  attn_fwd<<<dim3(32, HK, B_), blk, 0, stream>>>(Qp, Kp, Vt, AO, linv);
  attn_aw<<<dim3(32, HK, B_), blk, 0, stream>>>(Qp, Kp, linv, aw);

  ln_fwd<<<dim3(M), blk, 0, stream>>>(AO, gamma, beta, LNo);
  gemm_bt<u16, 0><<<dim3(M / 128, 7), blk, 0, stream>>>(LNo, Wo, out, M, EMBED, EMBED);
}

// Round 4
// 213.466 us; speedup vs baseline: 1.8077x; 1.5043x over previous
//
#include <hip/hip_runtime.h>

#define B_    2
#define N_    2048
#define EMBED 896
#define HQ    16
#define HK    4
#define D_    56
#define DP    64

typedef unsigned short u16;
typedef unsigned int   u32;
typedef __attribute__((ext_vector_type(8))) short bf16x8;
typedef __attribute__((ext_vector_type(4))) float f32x4;

__device__ __forceinline__ u16 f2bf(float f) {
  u32 u = __builtin_bit_cast(u32, f);
  return (u16)((u + 0x7FFFu + ((u >> 16) & 1u)) >> 16);
}

#define EXP2F(x) __builtin_amdgcn_exp2f(x)

// QSCALE = (1/sqrt(56)) * log2(e); folded into Q so softmax uses exp2
#define QSCALE 0.19278822f

// ---------------------------------------------------------------------------
// Bulk f32 -> bf16 conversion of q/k/v inputs and the four weights.
// 4 elems/thread, fully coalesced.
// ---------------------------------------------------------------------------
#define SEG_IN  3670016u   // 2*2048*896
#define SEG_WQ  802816u    // 896*896
#define SEG_WK  200704u    // 224*896

__global__ __launch_bounds__(256) void to_bf16(
    const float* __restrict__ q, const float* __restrict__ k,
    const float* __restrict__ v, const float* __restrict__ wq,
    const float* __restrict__ wk, const float* __restrict__ wv,
    const float* __restrict__ wo, u16* __restrict__ qb, u16* __restrict__ kb,
    u16* __restrict__ vb, u16* __restrict__ wqb, u16* __restrict__ wkb,
    u16* __restrict__ wvb, u16* __restrict__ wob) {
  size_t e = ((size_t)blockIdx.x * 256 + threadIdx.x) * 4;
  const float* src;
  u16* dst;
  size_t off;
  if (e < SEG_IN)            { src = q;  dst = qb;  off = e; }
  else if (e < 2 * (size_t)SEG_IN) { src = k;  dst = kb;  off = e - SEG_IN; }
  else if (e < 3 * (size_t)SEG_IN) { src = v;  dst = vb;  off = e - 2 * (size_t)SEG_IN; }
  else {
    size_t r = e - 3 * (size_t)SEG_IN;
    if (r < SEG_WQ)                    { src = wq; dst = wqb; off = r; }
    else if (r < SEG_WQ + SEG_WK)      { src = wk; dst = wkb; off = r - SEG_WQ; }
    else if (r < SEG_WQ + 2 * SEG_WK)  { src = wv; dst = wvb; off = r - SEG_WQ - SEG_WK; }
    else                               { src = wo; dst = wob; off = r - SEG_WQ - 2 * SEG_WK; }
  }
  float4 v4 = *(const float4*)(src + off);
  uint2 pb;
  pb.x = (u32)f2bf(v4.x) | ((u32)f2bf(v4.y) << 16);
  pb.y = (u32)f2bf(v4.z) | ((u32)f2bf(v4.w) << 16);
  *(uint2*)(dst + off) = pb;
}

// ---------------------------------------------------------------------------
// Fused QKV projection GEMM. BM=128, BN=64, BK=64; grid (32, 22):
// y<14 -> Q n-tile, y<18 -> K n-tile, else V n-tile. bf16 A/B, reg-prefetch
// double buffering. Epilogue scatters to padded Qp/Kp/Vt (Q gets QSCALE).
// ---------------------------------------------------------------------------
__global__ __launch_bounds__(256) void proj_gemm(
    const u16* __restrict__ qb, const u16* __restrict__ kb,
    const u16* __restrict__ vb, const u16* __restrict__ Wqb,
    const u16* __restrict__ Wkb, const u16* __restrict__ Wvb,
    u16* __restrict__ Qp, u16* __restrict__ Kp, u16* __restrict__ Vt) {
  __shared__ __align__(16) u16 As[128][72];
  __shared__ __align__(16) u16 Bs[64][72];
  const int t = threadIdx.x;
  const int m0 = blockIdx.x * 128;
  const int y = blockIdx.y;
  int p, nt;
  if (y < 14)      { p = 0; nt = y; }
  else if (y < 18) { p = 1; nt = y - 14; }
  else             { p = 2; nt = y - 18; }
  const u16* A = p == 0 ? qb : (p == 1 ? kb : vb);
  const u16* W = p == 0 ? Wqb : (p == 1 ? Wkb : Wvb);
  const int Nproj = p == 0 ? 896 : 224;
  const int wn0 = nt * 64;

  const int w = t >> 6, lane = t & 63;
  const int fr = lane & 15, fg = lane >> 4;
  const int wr = w * 32;

  f32x4 acc[2][4] = {};
  int4 ar[4], br[2];

  const int ra = (t * 4) >> 3;          // A stage rows (4 int4/thread)
  const int ca = ((t * 4) & 7) * 8;     // 4 consecutive int4 => same row? no:
  // use flat = i*256+t mapping instead (computed inline below)

#define LOAD_A(k0_)                                                            \
  _Pragma("unroll") for (int i = 0; i < 4; i++) {                              \
    int flat = i * 256 + t;                                                    \
    int r = flat >> 3, c = (flat & 7) * 8;                                     \
    ar[i] = *(const int4*)(A + (size_t)(m0 + r) * EMBED + (k0_) + c);          \
  }
#define LOAD_B(k0_)                                                            \
  _Pragma("unroll") for (int i = 0; i < 2; i++) {                              \
    int flat = i * 256 + t;                                                    \
    int r = flat >> 3, c = (flat & 7) * 8;                                     \
    int4 z = {0, 0, 0, 0};                                                     \
    if (wn0 + r < Nproj)                                                       \
      z = *(const int4*)(W + (size_t)(wn0 + r) * EMBED + (k0_) + c);           \
    br[i] = z;                                                                 \
  }

  LOAD_A(0);
  LOAD_B(0);
  for (int k0 = 0; k0 < EMBED; k0 += 64) {
    __syncthreads();
#pragma unroll
    for (int i = 0; i < 4; i++) {
      int flat = i * 256 + t;
      *(int4*)&As[flat >> 3][(flat & 7) * 8] = ar[i];
    }
#pragma unroll
    for (int i = 0; i < 2; i++) {
      int flat = i * 256 + t;
      *(int4*)&Bs[flat >> 3][(flat & 7) * 8] = br[i];
    }
    __syncthreads();
    if (k0 + 64 < EMBED) {
      LOAD_A(k0 + 64);
      LOAD_B(k0 + 64);
    }
#pragma unroll
    for (int kk = 0; kk < 2; kk++) {
      bf16x8 af[2], bfv[4];
#pragma unroll
      for (int mf = 0; mf < 2; mf++)
        af[mf] = *(const bf16x8*)&As[wr + mf * 16 + fr][kk * 32 + fg * 8];
#pragma unroll
      for (int nf = 0; nf < 4; nf++)
        bfv[nf] = *(const bf16x8*)&Bs[nf * 16 + fr][kk * 32 + fg * 8];
#pragma unroll
      for (int mf = 0; mf < 2; mf++)
#pragma unroll
        for (int nf = 0; nf < 4; nf++)
          acc[mf][nf] = __builtin_amdgcn_mfma_f32_16x16x32_bf16(
              af[mf], bfv[nf], acc[mf][nf], 0, 0, 0);
    }
  }

#pragma unroll
  for (int nf = 0; nf < 4; nf++) {
    int col = wn0 + nf * 16 + fr;
    if (col < Nproj) {
      int hh = col / 56, d = col - hh * 56;
#pragma unroll
      for (int mf = 0; mf < 2; mf++)
#pragma unroll
        for (int r = 0; r < 4; r++) {
          int row = m0 + wr + mf * 16 + fg * 4 + r;
          int bb = row >> 11, nn = row & 2047;
          float vv = acc[mf][nf][r];
          if (p == 0)
            Qp[((size_t)((bb * 16 + hh) * 2048 + nn)) * 64 + d] = f2bf(vv * QSCALE);
          else if (p == 1)
            Kp[((size_t)((bb * 4 + hh) * 2048 + nn)) * 64 + d] = f2bf(vv);
          else
            Vt[((size_t)((bb * 4 + hh) * 64 + d)) * 2048 + nn] = f2bf(vv);
        }
    }
  }
}

// ---------------------------------------------------------------------------
// Output projection: out = LNo (bf16) @ Wo^T. BM=128, BN=64, grid (32,14).
// ---------------------------------------------------------------------------
__global__ __launch_bounds__(256) void gemm_wo(const u16* __restrict__ A,
                                               const u16* __restrict__ W,
                                               float* __restrict__ C) {
  __shared__ __align__(16) u16 As[128][72];
  __shared__ __align__(16) u16 Bs[64][72];
  const int t = threadIdx.x;
  const int m0 = blockIdx.x * 128;
  const int wn0 = blockIdx.y * 64;
  const int w = t >> 6, lane = t & 63;
  const int fr = lane & 15, fg = lane >> 4;
  const int wr = w * 32;

  f32x4 acc[2][4] = {};
  int4 ar[4], br[2];

#define LOAD_A2(k0_)                                                           \
  _Pragma("unroll") for (int i = 0; i < 4; i++) {                              \
    int flat = i * 256 + t;                                                    \
    int r = flat >> 3, c = (flat & 7) * 8;                                     \
    ar[i] = *(const int4*)(A + (size_t)(m0 + r) * EMBED + (k0_) + c);          \
  }
#define LOAD_B2(k0_)                                                           \
  _Pragma("unroll") for (int i = 0; i < 2; i++) {                              \
    int flat = i * 256 + t;                                                    \
    int r = flat >> 3, c = (flat & 7) * 8;                                     \
    br[i] = *(const int4*)(W + (size_t)(wn0 + r) * EMBED + (k0_) + c);         \
  }

  LOAD_A2(0);
  LOAD_B2(0);
  for (int k0 = 0; k0 < EMBED; k0 += 64) {
    __syncthreads();
#pragma unroll
    for (int i = 0; i < 4; i++) {
      int flat = i * 256 + t;
      *(int4*)&As[flat >> 3][(flat & 7) * 8] = ar[i];
    }
#pragma unroll
    for (int i = 0; i < 2; i++) {
      int flat = i * 256 + t;
      *(int4*)&Bs[flat >> 3][(flat & 7) * 8] = br[i];
    }
    __syncthreads();
    if (k0 + 64 < EMBED) {
      LOAD_A2(k0 + 64);
      LOAD_B2(k0 + 64);
    }
#pragma unroll
    for (int kk = 0; kk < 2; kk++) {
      bf16x8 af[2], bfv[4];
#pragma unroll
      for (int mf = 0; mf < 2; mf++)
        af[mf] = *(const bf16x8*)&As[wr + mf * 16 + fr][kk * 32 + fg * 8];
#pragma unroll
      for (int nf = 0; nf < 4; nf++)
        bfv[nf] = *(const bf16x8*)&Bs[nf * 16 + fr][kk * 32 + fg * 8];
#pragma unroll
      for (int mf = 0; mf < 2; mf++)
#pragma unroll
        for (int nf = 0; nf < 4; nf++)
          acc[mf][nf] = __builtin_amdgcn_mfma_f32_16x16x32_bf16(
              af[mf], bfv[nf], acc[mf][nf], 0, 0, 0);
    }
  }

#pragma unroll
  for (int nf = 0; nf < 4; nf++) {
    int col = wn0 + nf * 16 + fr;
#pragma unroll
    for (int mf = 0; mf < 2; mf++)
#pragma unroll
      for (int r = 0; r < 4; r++) {
        int row = m0 + wr + mf * 16 + fg * 4 + r;
        C[(size_t)row * EMBED + col] = acc[mf][nf][r];
      }
  }
}

// ---------------------------------------------------------------------------
// Pass A: causal flash attention. Block = (strip-pair, hk, b); 4 waves, one
// head per wave sharing K/V LDS staging. 32-row q strips paired (s, 63-s).
// ---------------------------------------------------------------------------
__global__ __launch_bounds__(256) void attn_fwd(const u16* __restrict__ Qp,
                                                const u16* __restrict__ Kp,
                                                const u16* __restrict__ Vt,
                                                float* __restrict__ AO,
                                                float* __restrict__ linv_g) {
  const int p = blockIdx.x, hk = blockIdx.y, b = blockIdx.z;
  const int t = threadIdx.x, w = t >> 6, lane = t & 63;
  const int fr = lane & 15, fg = lane >> 4;
  const int h = hk * 4 + w;

  __shared__ __align__(16) u16 Ks[64][72];
  __shared__ __align__(16) u16 Vs[64][72];
  __shared__ __align__(16) u16 Ps[4][32][72];

  const u16* Qh = Qp + (size_t)(b * HQ + h) * N_ * DP;
  const u16* Kh = Kp + (size_t)(b * HK + hk) * N_ * DP;
  const u16* Vh = Vt + (size_t)(b * HK + hk) * DP * N_;
  float* linv_h = linv_g + (size_t)(b * HQ + h) * N_;

  const int f0 = t * 2, f1 = t * 2 + 1;

  for (int half = 0; half < 2; ++half) {
    const int s = half ? (63 - p) : p;
    const int nt = (s >> 1) + 1;

    bf16x8 qf[2][2];
#pragma unroll
    for (int m = 0; m < 2; m++)
#pragma unroll
      for (int kk = 0; kk < 2; kk++)
        qf[m][kk] = *(const bf16x8*)(Qh + (size_t)(s * 32 + m * 16 + fr) * DP +
                                     kk * 32 + fg * 8);

    f32x4 oacc[2][4] = {};
    float l_acc[2][4] = {};

    int4 kr0, kr1, vr0, vr1;
    {
      kr0 = *(const int4*)(Kh + f0 * 8);
      kr1 = *(const int4*)(Kh + f1 * 8);
      vr0 = *(const int4*)(Vh + (size_t)(f0 >> 3) * N_ + (f0 & 7) * 8);
      vr1 = *(const int4*)(Vh + (size_t)(f1 >> 3) * N_ + (f1 & 7) * 8);
    }

    for (int tt = 0; tt < nt; ++tt) {
      __syncthreads();
      *(int4*)&Ks[f0 >> 3][(f0 & 7) * 8] = kr0;
      *(int4*)&Ks[f1 >> 3][(f1 & 7) * 8] = kr1;
      *(int4*)&Vs[f0 >> 3][(f0 & 7) * 8] = vr0;
      *(int4*)&Vs[f1 >> 3][(f1 & 7) * 8] = vr1;
      __syncthreads();
      if (tt + 1 < nt) {
        const u16* Kb = Kh + (size_t)(tt + 1) * 64 * DP;
        kr0 = *(const int4*)(Kb + f0 * 8);
        kr1 = *(const int4*)(Kb + f1 * 8);
        const u16* Vb = Vh + (tt + 1) * 64;
        vr0 = *(const int4*)(Vb + (size_t)(f0 >> 3) * N_ + (f0 & 7) * 8);
        vr1 = *(const int4*)(Vb + (size_t)(f1 >> 3) * N_ + (f1 & 7) * 8);
      }

      f32x4 sacc[2][4] = {};
#pragma unroll
      for (int kk = 0; kk < 2; kk++) {
        bf16x8 bk[4];
#pragma unroll
        for (int jf = 0; jf < 4; jf++)
          bk[jf] = *(const bf16x8*)&Ks[jf * 16 + fr][kk * 32 + fg * 8];
#pragma unroll
        for (int m = 0; m < 2; m++)
#pragma unroll
          for (int jf = 0; jf < 4; jf++)
            sacc[m][jf] = __builtin_amdgcn_mfma_f32_16x16x32_bf16(
                qf[m][kk], bk[jf], sacc[m][jf], 0, 0, 0);
      }

      if (tt == nt - 1) {
#pragma unroll
        for (int m = 0; m < 2; m++)
#pragma unroll
          for (int jf = 0; jf < 4; jf++)
#pragma unroll
            for (int r = 0; r < 4; r++) {
              int gi = s * 32 + m * 16 + fg * 4 + r;
              int gj = tt * 64 + jf * 16 + fr;
              float pv = (gj <= gi) ? EXP2F(sacc[m][jf][r]) : 0.f;
              l_acc[m][r] += pv;
              Ps[w][m * 16 + fg * 4 + r][jf * 16 + fr] = f2bf(pv);
            }
      } else {
#pragma unroll
        for (int m = 0; m < 2; m++)
#pragma unroll
          for (int jf = 0; jf < 4; jf++)
#pragma unroll
            for (int r = 0; r < 4; r++) {
              float pv = EXP2F(sacc[m][jf][r]);
              l_acc[m][r] += pv;
              Ps[w][m * 16 + fg * 4 + r][jf * 16 + fr] = f2bf(pv);
            }
      }

#pragma unroll
      for (int kk = 0; kk < 2; kk++) {
        bf16x8 ap[2], bv[4];
#pragma unroll
        for (int m = 0; m < 2; m++)
          ap[m] = *(const bf16x8*)&Ps[w][m * 16 + fr][kk * 32 + fg * 8];
#pragma unroll
        for (int df = 0; df < 4; df++)
          bv[df] = *(const bf16x8*)&Vs[df * 16 + fr][kk * 32 + fg * 8];
#pragma unroll
        for (int m = 0; m < 2; m++)
#pragma unroll
          for (int df = 0; df < 4; df++)
            oacc[m][df] = __builtin_amdgcn_mfma_f32_16x16x32_bf16(
                ap[m], bv[df], oacc[m][df], 0, 0, 0);
      }
    }

#pragma unroll
    for (int m = 0; m < 2; m++)
#pragma unroll
      for (int r = 0; r < 4; r++) {
        float v = l_acc[m][r];
        v += __shfl_xor(v, 1);
        v += __shfl_xor(v, 2);
        v += __shfl_xor(v, 4);
        v += __shfl_xor(v, 8);
        l_acc[m][r] = 1.0f / v;
      }
#pragma unroll
    for (int m = 0; m < 2; m++)
#pragma unroll
      for (int df = 0; df < 4; df++) {
        int d = df * 16 + fr;
        if (d < D_) {
#pragma unroll
          for (int r = 0; r < 4; r++) {
            int gi = s * 32 + m * 16 + fg * 4 + r;
            AO[((size_t)b * N_ + gi) * EMBED + h * D_ + d] =
                oacc[m][df][r] * l_acc[m][r];
          }
        }
      }
    if (fr == 0) {
#pragma unroll
      for (int m = 0; m < 2; m++)
#pragma unroll
        for (int r = 0; r < 4; r++)
          linv_h[s * 32 + m * 16 + fg * 4 + r] = l_acc[m][r];
    }
  }
}

// ---------------------------------------------------------------------------
// Pass B: attention-weight column means via transposed scores T = K*Q^T.
// ---------------------------------------------------------------------------
struct QTile {
  bf16x8 q[4][2];
  float li[4];
};

#define LOADQ(dst, rt_)                                                        \
  {                                                                            \
    _Pragma("unroll") for (int ifr = 0; ifr < 4; ifr++) {                      \
      _Pragma("unroll") for (int kk = 0; kk < 2; kk++)                         \
          dst.q[ifr][kk] = *(const bf16x8*)(Qh +                               \
              (size_t)((rt_)*64 + ifr * 16 + fr) * DP + kk * 32 + fg * 8);     \
      dst.li[ifr] = linv_h[(rt_)*64 + ifr * 16 + fr];                          \
    }                                                                          \
  }

#define COMPUTET(src, rt_)                                                     \
  {                                                                            \
    f32x4 tacc[2][4] = {};                                                     \
    _Pragma("unroll") for (int kk = 0; kk < 2; kk++)                           \
        _Pragma("unroll") for (int jm = 0; jm < 2; jm++)                       \
        _Pragma("unroll") for (int ifr = 0; ifr < 4; ifr++)                    \
            tacc[jm][ifr] = __builtin_amdgcn_mfma_f32_16x16x32_bf16(           \
                kf[jm][kk], src.q[ifr][kk], tacc[jm][ifr], 0, 0, 0);           \
    if ((rt_) == rt0) {                                                        \
      _Pragma("unroll") for (int jm = 0; jm < 2; jm++)                         \
          _Pragma("unroll") for (int ifr = 0; ifr < 4; ifr++)                  \
          _Pragma("unroll") for (int r = 0; r < 4; r++) {                      \
        int gi = (rt_)*64 + ifr * 16 + fr;                                     \
        int gj = ct * 32 + jm * 16 + fg * 4 + r;                               \
        if (gi >= gj)                                                          \
          s_acc[jm][r] += EXP2F(tacc[jm][ifr][r]) * src.li[ifr];               \
      }                                                                        \
    } else {                                                                   \
      _Pragma("unroll") for (int jm = 0; jm < 2; jm++)                         \
          _Pragma("unroll") for (int ifr = 0; ifr < 4; ifr++)                  \
          _Pragma("unroll") for (int r = 0; r < 4; r++)                        \
              s_acc[jm][r] += EXP2F(tacc[jm][ifr][r]) * src.li[ifr];           \
    }                                                                          \
  }

__global__ __launch_bounds__(256) void attn_aw(const u16* __restrict__ Qp,
                                               const u16* __restrict__ Kp,
                                               const float* __restrict__ linv_g,
                                               float* __restrict__ aw) {
  const int p = blockIdx.x, hk = blockIdx.y, b = blockIdx.z;
  const int t = threadIdx.x, w = t >> 6, lane = t & 63;
  const int fr = lane & 15, fg = lane >> 4;
  const int h = hk * 4 + w;

  const u16* Qh = Qp + (size_t)(b * HQ + h) * N_ * DP;
  const u16* Kh = Kp + (size_t)(b * HK + hk) * N_ * DP;
  const float* linv_h = linv_g + (size_t)(b * HQ + h) * N_;

  for (int half = 0; half < 2; ++half) {
    const int ct = half ? (63 - p) : p;
    const int rt0 = ct >> 1;

    bf16x8 kf[2][2];
#pragma unroll
    for (int jm = 0; jm < 2; jm++)
#pragma unroll
      for (int kk = 0; kk < 2; kk++)
        kf[jm][kk] = *(const bf16x8*)(Kh + (size_t)(ct * 32 + jm * 16 + fr) * DP +
                                      kk * 32 + fg * 8);

    float s_acc[2][4] = {};
    QTile qa, qb;
    LOADQ(qa, rt0);
    int rt = rt0;
    while (true) {
      if (rt + 1 <= 31) LOADQ(qb, rt + 1);
      COMPUTET(qa, rt);
      rt++;
      if (rt > 31) break;
      if (rt + 1 <= 31) LOADQ(qa, rt + 1);
      COMPUTET(qb, rt);
      rt++;
      if (rt > 31) break;
    }

#pragma unroll
    for (int jm = 0; jm < 2; jm++)
#pragma unroll
      for (int r = 0; r < 4; r++) {
        float v = s_acc[jm][r];
        v += __shfl_xor(v, 1);
        v += __shfl_xor(v, 2);
        v += __shfl_xor(v, 4);
        v += __shfl_xor(v, 8);
        if (fr == 0) {
          int gj = ct * 32 + jm * 16 + fg * 4 + r;
          aw[((size_t)b * N_ + gj) * HQ + h] = v * (1.0f / N_);
        }
      }
  }
}

// ---------------------------------------------------------------------------
// LayerNorm over EMBED, one block per row; bf16 output for the Wo GEMM.
// ---------------------------------------------------------------------------
__global__ __launch_bounds__(256) void ln_fwd(const float* __restrict__ AO,
                                              const float* __restrict__ gamma,
                                              const float* __restrict__ beta,
                                              u16* __restrict__ out) {
  const int row = blockIdx.x;
  const float* x = AO + (size_t)row * EMBED;
  const int t = threadIdx.x;
  float s = 0.f, s2 = 0.f;
  float v[4];
#pragma unroll
  for (int i = 0; i < 4; i++) {
    int c = t + 256 * i;
    v[i] = (c < EMBED) ? x[c] : 0.f;
    s += v[i];
    s2 += v[i] * v[i];
  }
#pragma unroll
  for (int m = 1; m <= 32; m <<= 1) {
    s += __shfl_xor(s, m);
    s2 += __shfl_xor(s2, m);
  }
  __shared__ float red[8];
  const int w = t >> 6, lane = t & 63;
  if (lane == 0) {
    red[w] = s;
    red[4 + w] = s2;
  }
  __syncthreads();
  s = red[0] + red[1] + red[2] + red[3];
  s2 = red[4] + red[5] + red[6] + red[7];
  const float mu = s * (1.0f / EMBED);
  const float var = s2 * (1.0f / EMBED) - mu * mu;
  const float rs = rsqrtf(var + 1e-5f);
#pragma unroll
  for (int i = 0; i < 4; i++) {
    int c = t + 256 * i;
    if (c < EMBED)
      out[(size_t)row * EMBED + c] = f2bf((v[i] - mu) * rs * gamma[c] + beta[c]);
  }
}

// ---------------------------------------------------------------------------
extern "C" void kernel_launch(void* const* d_in, const int* in_sizes, int n_in,
                              void* d_out, int out_size, void* d_ws,
                              size_t ws_size, hipStream_t stream) {
  (void)in_sizes; (void)n_in; (void)out_size; (void)ws_size;
  const float* query = (const float*)d_in[0];
  const float* key   = (const float*)d_in[1];
  const float* value = (const float*)d_in[2];
  const float* Wq    = (const float*)d_in[3];
  const float* Wk    = (const float*)d_in[4];
  const float* Wv    = (const float*)d_in[5];
  const float* Wo    = (const float*)d_in[6];
  const float* gamma = (const float*)d_in[7];
  const float* beta  = (const float*)d_in[8];

  float* out = (float*)d_out;                   // (b, n, EMBED) f32
  float* aw  = out + (size_t)B_ * N_ * EMBED;   // (b, s, HQ)   f32

  char* ws = (char*)d_ws;
  u16* Qp = (u16*)ws;        ws += (size_t)B_ * HQ * N_ * DP * 2;   // 8.39 MB
  u16* Kp = (u16*)ws;        ws += (size_t)B_ * HK * N_ * DP * 2;   // 2.10 MB
  u16* Vt = (u16*)ws;        ws += (size_t)B_ * HK * N_ * DP * 2;   // 2.10 MB
  float* linv = (float*)ws;  ws += (size_t)B_ * HQ * N_ * 4;        // 0.26 MB
  u16* Wqb = (u16*)ws;       ws += (size_t)SEG_WQ * 2;              // 1.61 MB
  u16* Wkb = (u16*)ws;       ws += (size_t)SEG_WK * 2;              // 0.40 MB
  u16* Wvb = (u16*)ws;       ws += (size_t)SEG_WK * 2;              // 0.40 MB
  u16* Wob = (u16*)ws;       ws += (size_t)SEG_WQ * 2;              // 1.61 MB
  char* region = ws;         // 22.02 MB region, two lifetimes:
  u16* qb = (u16*)region;                        // phase 1: qb/kb/vb
  u16* kb = qb + (size_t)SEG_IN;
  u16* vb = kb + (size_t)SEG_IN;
  float* AO = (float*)region;                    // phase 2: AO + LNo
  u16* LNo = (u16*)(region + (size_t)B_ * N_ * EMBED * 4);

  const size_t pad_bytes =
      ((size_t)B_ * HQ * N_ * DP + 2 * (size_t)B_ * HK * N_ * DP) * 2;
  (void)hipMemsetAsync(Qp, 0, pad_bytes, stream);  // zero d=56..63 pads

  dim3 blk(256);
  const int M = B_ * N_;  // 4096

  to_bf16<<<dim3(12712), blk, 0, stream>>>(query, key, value, Wq, Wk, Wv, Wo,
                                           qb, kb, vb, Wqb, Wkb, Wvb, Wob);

  proj_gemm<<<dim3(M / 128, 22), blk, 0, stream>>>(qb, kb, vb, Wqb, Wkb, Wvb,
                                                   Qp, Kp, Vt);

  attn_fwd<<<dim3(32, HK, B_), blk, 0, stream>>>(Qp, Kp, Vt, AO, linv);
  attn_aw<<<dim3(32, HK, B_), blk, 0, stream>>>(Qp, Kp, linv, aw);

  ln_fwd<<<dim3(M), blk, 0, stream>>>(AO, gamma, beta, LNo);
  gemm_wo<<<dim3(M / 128, 14), blk, 0, stream>>>(LNo, Wob, out);
}

// Round 5
// 203.540 us; speedup vs baseline: 1.8959x; 1.0488x over previous
//
#include <hip/hip_runtime.h>

#define B_    2
#define N_    2048
#define EMBED 896
#define HQ    16
#define HK    4
#define D_    56
#define DP    64

typedef unsigned short u16;
typedef unsigned int   u32;
typedef __attribute__((ext_vector_type(8))) short bf16x8;
typedef __attribute__((ext_vector_type(4))) float f32x4;

__device__ __forceinline__ u16 f2bf(float f) {
  u32 u = __builtin_bit_cast(u32, f);
  return (u16)((u + 0x7FFFu + ((u >> 16) & 1u)) >> 16);
}

#define EXP2F(x) __builtin_amdgcn_exp2f(x)

// QSCALE = (1/sqrt(56)) * log2(e); folded into Q so softmax uses exp2
#define QSCALE 0.19278822f

// ---------------------------------------------------------------------------
// Bulk f32 -> bf16 conversion of q/k/v inputs and the four weights.
// ---------------------------------------------------------------------------
#define SEG_IN  3670016u   // 2*2048*896
#define SEG_WQ  802816u    // 896*896
#define SEG_WK  200704u    // 224*896

__global__ __launch_bounds__(256) void to_bf16(
    const float* __restrict__ q, const float* __restrict__ k,
    const float* __restrict__ v, const float* __restrict__ wq,
    const float* __restrict__ wk, const float* __restrict__ wv,
    const float* __restrict__ wo, u16* __restrict__ qb, u16* __restrict__ kb,
    u16* __restrict__ vb, u16* __restrict__ wqb, u16* __restrict__ wkb,
    u16* __restrict__ wvb, u16* __restrict__ wob) {
  size_t e = ((size_t)blockIdx.x * 256 + threadIdx.x) * 4;
  const float* src;
  u16* dst;
  size_t off;
  if (e < SEG_IN)            { src = q;  dst = qb;  off = e; }
  else if (e < 2 * (size_t)SEG_IN) { src = k;  dst = kb;  off = e - SEG_IN; }
  else if (e < 3 * (size_t)SEG_IN) { src = v;  dst = vb;  off = e - 2 * (size_t)SEG_IN; }
  else {
    size_t r = e - 3 * (size_t)SEG_IN;
    if (r < SEG_WQ)                    { src = wq; dst = wqb; off = r; }
    else if (r < SEG_WQ + SEG_WK)      { src = wk; dst = wkb; off = r - SEG_WQ; }
    else if (r < SEG_WQ + 2 * SEG_WK)  { src = wv; dst = wvb; off = r - SEG_WQ - SEG_WK; }
    else                               { src = wo; dst = wob; off = r - SEG_WQ - 2 * SEG_WK; }
  }
  float4 v4 = *(const float4*)(src + off);
  uint2 pb;
  pb.x = (u32)f2bf(v4.x) | ((u32)f2bf(v4.y) << 16);
  pb.y = (u32)f2bf(v4.z) | ((u32)f2bf(v4.w) << 16);
  *(uint2*)(dst + off) = pb;
}

// ---------------------------------------------------------------------------
// Fused QKV projection GEMM. BM=128, BN=64, BK=64; grid (32, 22).
// Double-buffered LDS, 2-tile register prefetch, ONE barrier per K-step.
// V epilogue transposed through LDS for coalesced Vt writes.
// ---------------------------------------------------------------------------
#define NT_K 14  // 896/64

__global__ __launch_bounds__(256) void proj_gemm(
    const u16* __restrict__ qb, const u16* __restrict__ kb,
    const u16* __restrict__ vb, const u16* __restrict__ Wqb,
    const u16* __restrict__ Wkb, const u16* __restrict__ Wvb,
    u16* __restrict__ Qp, u16* __restrict__ Kp, u16* __restrict__ Vt) {
  __shared__ __align__(16) u16 As[2][128][68];
  __shared__ __align__(16) u16 Bs[2][64][68];
  const int t = threadIdx.x;
  const int m0 = blockIdx.x * 128;
  const int y = blockIdx.y;
  int p, nt;
  if (y < 14)      { p = 0; nt = y; }
  else if (y < 18) { p = 1; nt = y - 14; }
  else             { p = 2; nt = y - 18; }
  const u16* A = p == 0 ? qb : (p == 1 ? kb : vb);
  const u16* W = p == 0 ? Wqb : (p == 1 ? Wkb : Wvb);
  const int Nproj = p == 0 ? 896 : 224;
  const int wn0 = nt * 64;

  const int w = t >> 6, lane = t & 63;
  const int fr = lane & 15, fg = lane >> 4;
  const int wr = w * 32;

  f32x4 acc[2][4] = {};
  int4 ar[4], br[2];

#define PJ_LOAD_A(k0_)                                                         \
  _Pragma("unroll") for (int i = 0; i < 4; i++) {                              \
    int flat = i * 256 + t;                                                    \
    int r = flat >> 3, c = (flat & 7) * 8;                                     \
    ar[i] = *(const int4*)(A + (size_t)(m0 + r) * EMBED + (k0_) + c);          \
  }
#define PJ_LOAD_B(k0_)                                                         \
  _Pragma("unroll") for (int i = 0; i < 2; i++) {                              \
    int flat = i * 256 + t;                                                    \
    int r = flat >> 3, c = (flat & 7) * 8;                                     \
    int4 z = {0, 0, 0, 0};                                                     \
    if (wn0 + r < Nproj)                                                       \
      z = *(const int4*)(W + (size_t)(wn0 + r) * EMBED + (k0_) + c);           \
    br[i] = z;                                                                 \
  }
#define PJ_WRITE(buf_)                                                         \
  {                                                                            \
    _Pragma("unroll") for (int i = 0; i < 4; i++) {                            \
      int flat = i * 256 + t;                                                  \
      *(int4*)&As[buf_][flat >> 3][(flat & 7) * 8] = ar[i];                    \
    }                                                                          \
    _Pragma("unroll") for (int i = 0; i < 2; i++) {                            \
      int flat = i * 256 + t;                                                  \
      *(int4*)&Bs[buf_][flat >> 3][(flat & 7) * 8] = br[i];                    \
    }                                                                          \
  }

  PJ_LOAD_A(0); PJ_LOAD_B(0);
  PJ_WRITE(0);
  PJ_LOAD_A(64); PJ_LOAD_B(64);
  __syncthreads();

  for (int it = 0; it < NT_K; ++it) {
    const int cur = it & 1;
    if (it + 1 < NT_K) PJ_WRITE(cur ^ 1);         // regs loaded last iter
    if (it + 2 < NT_K) { PJ_LOAD_A((it + 2) * 64); PJ_LOAD_B((it + 2) * 64); }
#pragma unroll
    for (int kk = 0; kk < 2; kk++) {
      bf16x8 af[2], bfv[4];
#pragma unroll
      for (int mf = 0; mf < 2; mf++)
        af[mf] = *(const bf16x8*)&As[cur][wr + mf * 16 + fr][kk * 32 + fg * 8];
#pragma unroll
      for (int nf = 0; nf < 4; nf++)
        bfv[nf] = *(const bf16x8*)&Bs[cur][nf * 16 + fr][kk * 32 + fg * 8];
#pragma unroll
      for (int mf = 0; mf < 2; mf++)
#pragma unroll
        for (int nf = 0; nf < 4; nf++)
          acc[mf][nf] = __builtin_amdgcn_mfma_f32_16x16x32_bf16(
              af[mf], bfv[nf], acc[mf][nf], 0, 0, 0);
    }
    __syncthreads();
  }

  if (p < 2) {
    // direct scatter (rows of padded Qp/Kp; 32B chunks, acceptable)
#pragma unroll
    for (int nf = 0; nf < 4; nf++) {
      int col = wn0 + nf * 16 + fr;
      if (col < Nproj) {
        int hh = col / 56, d = col - hh * 56;
#pragma unroll
        for (int mf = 0; mf < 2; mf++)
#pragma unroll
          for (int r = 0; r < 4; r++) {
            int row = m0 + wr + mf * 16 + fg * 4 + r;
            int bb = row >> 11, nn = row & 2047;
            float vv = acc[mf][nf][r];
            if (p == 0)
              Qp[((size_t)((bb * 16 + hh) * 2048 + nn)) * 64 + d] =
                  f2bf(vv * QSCALE);
            else
              Kp[((size_t)((bb * 4 + hh) * 2048 + nn)) * 64 + d] = f2bf(vv);
          }
      }
    }
  } else {
    // V: transpose through LDS, then coalesced 256B-contiguous stores
    u16* Traw = &As[0][0][0];  // reuse; need 64*136 = 8704 u16
#define TS(r_, c_) Traw[(r_)*136 + (c_)]
#pragma unroll
    for (int nf = 0; nf < 4; nf++)
#pragma unroll
      for (int mf = 0; mf < 2; mf++)
#pragma unroll
        for (int r = 0; r < 4; r++)
          TS(nf * 16 + fr, wr + mf * 16 + fg * 4 + r) = f2bf(acc[mf][nf][r]);
    __syncthreads();
    const int bb = m0 >> 11, n_base = m0 & 2047;
#pragma unroll
    for (int i = 0; i < 4; i++) {
      int flat = i * 256 + t;     // 0..1023
      int dr = flat >> 4;         // 0..63 (local V col)
      int c8 = (flat & 15) * 8;   // 0..120 (local row)
      int col = wn0 + dr;
      if (col < 224) {
        int hh = col / 56, d = col - hh * 56;
        *(int4*)(Vt + ((size_t)((bb * 4 + hh) * 64 + d)) * 2048 + n_base + c8) =
            *(int4*)&TS(dr, c8);
      }
    }
  }
}

// ---------------------------------------------------------------------------
// Output projection: out = LNo (bf16) @ Wo^T. BM=128, BN=64, grid (32,14).
// Same dbuf/prefetch structure.
// ---------------------------------------------------------------------------
__global__ __launch_bounds__(256) void gemm_wo(const u16* __restrict__ A,
                                               const u16* __restrict__ W,
                                               float* __restrict__ C) {
  __shared__ __align__(16) u16 As[2][128][68];
  __shared__ __align__(16) u16 Bs[2][64][68];
  const int t = threadIdx.x;
  const int m0 = blockIdx.x * 128;
  const int wn0 = blockIdx.y * 64;
  const int w = t >> 6, lane = t & 63;
  const int fr = lane & 15, fg = lane >> 4;
  const int wr = w * 32;

  f32x4 acc[2][4] = {};
  int4 ar[4], br[2];

#define WO_LOAD_A(k0_)                                                         \
  _Pragma("unroll") for (int i = 0; i < 4; i++) {                              \
    int flat = i * 256 + t;                                                    \
    int r = flat >> 3, c = (flat & 7) * 8;                                     \
    ar[i] = *(const int4*)(A + (size_t)(m0 + r) * EMBED + (k0_) + c);          \
  }
#define WO_LOAD_B(k0_)                                                         \
  _Pragma("unroll") for (int i = 0; i < 2; i++) {                              \
    int flat = i * 256 + t;                                                    \
    int r = flat >> 3, c = (flat & 7) * 8;                                     \
    br[i] = *(const int4*)(W + (size_t)(wn0 + r) * EMBED + (k0_) + c);         \
  }
#define WO_WRITE(buf_)                                                         \
  {                                                                            \
    _Pragma("unroll") for (int i = 0; i < 4; i++) {                            \
      int flat = i * 256 + t;                                                  \
      *(int4*)&As[buf_][flat >> 3][(flat & 7) * 8] = ar[i];                    \
    }                                                                          \
    _Pragma("unroll") for (int i = 0; i < 2; i++) {                            \
      int flat = i * 256 + t;                                                  \
      *(int4*)&Bs[buf_][flat >> 3][(flat & 7) * 8] = br[i];                    \
    }                                                                          \
  }

  WO_LOAD_A(0); WO_LOAD_B(0);
  WO_WRITE(0);
  WO_LOAD_A(64); WO_LOAD_B(64);
  __syncthreads();

  for (int it = 0; it < NT_K; ++it) {
    const int cur = it & 1;
    if (it + 1 < NT_K) WO_WRITE(cur ^ 1);
    if (it + 2 < NT_K) { WO_LOAD_A((it + 2) * 64); WO_LOAD_B((it + 2) * 64); }
#pragma unroll
    for (int kk = 0; kk < 2; kk++) {
      bf16x8 af[2], bfv[4];
#pragma unroll
      for (int mf = 0; mf < 2; mf++)
        af[mf] = *(const bf16x8*)&As[cur][wr + mf * 16 + fr][kk * 32 + fg * 8];
#pragma unroll
      for (int nf = 0; nf < 4; nf++)
        bfv[nf] = *(const bf16x8*)&Bs[cur][nf * 16 + fr][kk * 32 + fg * 8];
#pragma unroll
      for (int mf = 0; mf < 2; mf++)
#pragma unroll
        for (int nf = 0; nf < 4; nf++)
          acc[mf][nf] = __builtin_amdgcn_mfma_f32_16x16x32_bf16(
              af[mf], bfv[nf], acc[mf][nf], 0, 0, 0);
    }
    __syncthreads();
  }

#pragma unroll
  for (int nf = 0; nf < 4; nf++) {
    int col = wn0 + nf * 16 + fr;
#pragma unroll
    for (int mf = 0; mf < 2; mf++)
#pragma unroll
      for (int r = 0; r < 4; r++) {
        int row = m0 + wr + mf * 16 + fg * 4 + r;
        C[(size_t)row * EMBED + col] = acc[mf][nf][r];
      }
  }
}

// ---------------------------------------------------------------------------
// Pass A: causal flash attention. Block = (strip-pair, hk, b); 4 waves, one
// head per wave sharing K/V LDS staging. 32-row q strips paired (s, 63-s).
// ---------------------------------------------------------------------------
__global__ __launch_bounds__(256) void attn_fwd(const u16* __restrict__ Qp,
                                                const u16* __restrict__ Kp,
                                                const u16* __restrict__ Vt,
                                                float* __restrict__ AO,
                                                float* __restrict__ linv_g) {
  const int p = blockIdx.x, hk = blockIdx.y, b = blockIdx.z;
  const int t = threadIdx.x, w = t >> 6, lane = t & 63;
  const int fr = lane & 15, fg = lane >> 4;
  const int h = hk * 4 + w;

  __shared__ __align__(16) u16 Ks[64][72];
  __shared__ __align__(16) u16 Vs[64][72];
  __shared__ __align__(16) u16 Ps[4][32][72];

  const u16* Qh = Qp + (size_t)(b * HQ + h) * N_ * DP;
  const u16* Kh = Kp + (size_t)(b * HK + hk) * N_ * DP;
  const u16* Vh = Vt + (size_t)(b * HK + hk) * DP * N_;
  float* linv_h = linv_g + (size_t)(b * HQ + h) * N_;

  const int f0 = t * 2, f1 = t * 2 + 1;

  for (int half = 0; half < 2; ++half) {
    const int s = half ? (63 - p) : p;
    const int nt = (s >> 1) + 1;

    bf16x8 qf[2][2];
#pragma unroll
    for (int m = 0; m < 2; m++)
#pragma unroll
      for (int kk = 0; kk < 2; kk++)
        qf[m][kk] = *(const bf16x8*)(Qh + (size_t)(s * 32 + m * 16 + fr) * DP +
                                     kk * 32 + fg * 8);

    f32x4 oacc[2][4] = {};
    float l_acc[2][4] = {};

    int4 kr0, kr1, vr0, vr1;
    {
      kr0 = *(const int4*)(Kh + f0 * 8);
      kr1 = *(const int4*)(Kh + f1 * 8);
      vr0 = *(const int4*)(Vh + (size_t)(f0 >> 3) * N_ + (f0 & 7) * 8);
      vr1 = *(const int4*)(Vh + (size_t)(f1 >> 3) * N_ + (f1 & 7) * 8);
    }

    for (int tt = 0; tt < nt; ++tt) {
      __syncthreads();
      *(int4*)&Ks[f0 >> 3][(f0 & 7) * 8] = kr0;
      *(int4*)&Ks[f1 >> 3][(f1 & 7) * 8] = kr1;
      *(int4*)&Vs[f0 >> 3][(f0 & 7) * 8] = vr0;
      *(int4*)&Vs[f1 >> 3][(f1 & 7) * 8] = vr1;
      __syncthreads();
      if (tt + 1 < nt) {
        const u16* Kb = Kh + (size_t)(tt + 1) * 64 * DP;
        kr0 = *(const int4*)(Kb + f0 * 8);
        kr1 = *(const int4*)(Kb + f1 * 8);
        const u16* Vb = Vh + (tt + 1) * 64;
        vr0 = *(const int4*)(Vb + (size_t)(f0 >> 3) * N_ + (f0 & 7) * 8);
        vr1 = *(const int4*)(Vb + (size_t)(f1 >> 3) * N_ + (f1 & 7) * 8);
      }

      f32x4 sacc[2][4] = {};
#pragma unroll
      for (int kk = 0; kk < 2; kk++) {
        bf16x8 bk[4];
#pragma unroll
        for (int jf = 0; jf < 4; jf++)
          bk[jf] = *(const bf16x8*)&Ks[jf * 16 + fr][kk * 32 + fg * 8];
#pragma unroll
        for (int m = 0; m < 2; m++)
#pragma unroll
          for (int jf = 0; jf < 4; jf++)
            sacc[m][jf] = __builtin_amdgcn_mfma_f32_16x16x32_bf16(
                qf[m][kk], bk[jf], sacc[m][jf], 0, 0, 0);
      }

      if (tt == nt - 1) {
#pragma unroll
        for (int m = 0; m < 2; m++)
#pragma unroll
          for (int jf = 0; jf < 4; jf++)
#pragma unroll
            for (int r = 0; r < 4; r++) {
              int gi = s * 32 + m * 16 + fg * 4 + r;
              int gj = tt * 64 + jf * 16 + fr;
              float pv = (gj <= gi) ? EXP2F(sacc[m][jf][r]) : 0.f;
              l_acc[m][r] += pv;
              Ps[w][m * 16 + fg * 4 + r][jf * 16 + fr] = f2bf(pv);
            }
      } else {
#pragma unroll
        for (int m = 0; m < 2; m++)
#pragma unroll
          for (int jf = 0; jf < 4; jf++)
#pragma unroll
            for (int r = 0; r < 4; r++) {
              float pv = EXP2F(sacc[m][jf][r]);
              l_acc[m][r] += pv;
              Ps[w][m * 16 + fg * 4 + r][jf * 16 + fr] = f2bf(pv);
            }
      }

#pragma unroll
      for (int kk = 0; kk < 2; kk++) {
        bf16x8 ap[2], bv[4];
#pragma unroll
        for (int m = 0; m < 2; m++)
          ap[m] = *(const bf16x8*)&Ps[w][m * 16 + fr][kk * 32 + fg * 8];
#pragma unroll
        for (int df = 0; df < 4; df++)
          bv[df] = *(const bf16x8*)&Vs[df * 16 + fr][kk * 32 + fg * 8];
#pragma unroll
        for (int m = 0; m < 2; m++)
#pragma unroll
          for (int df = 0; df < 4; df++)
            oacc[m][df] = __builtin_amdgcn_mfma_f32_16x16x32_bf16(
                ap[m], bv[df], oacc[m][df], 0, 0, 0);
      }
    }

#pragma unroll
    for (int m = 0; m < 2; m++)
#pragma unroll
      for (int r = 0; r < 4; r++) {
        float v = l_acc[m][r];
        v += __shfl_xor(v, 1);
        v += __shfl_xor(v, 2);
        v += __shfl_xor(v, 4);
        v += __shfl_xor(v, 8);
        l_acc[m][r] = 1.0f / v;
      }
#pragma unroll
    for (int m = 0; m < 2; m++)
#pragma unroll
      for (int df = 0; df < 4; df++) {
        int d = df * 16 + fr;
        if (d < D_) {
#pragma unroll
          for (int r = 0; r < 4; r++) {
            int gi = s * 32 + m * 16 + fg * 4 + r;
            AO[((size_t)b * N_ + gi) * EMBED + h * D_ + d] =
                oacc[m][df][r] * l_acc[m][r];
          }
        }
      }
    if (fr == 0) {
#pragma unroll
      for (int m = 0; m < 2; m++)
#pragma unroll
        for (int r = 0; r < 4; r++)
          linv_h[s * 32 + m * 16 + fg * 4 + r] = l_acc[m][r];
    }
  }
}

// ---------------------------------------------------------------------------
// Pass B: attention-weight column means via transposed scores T = K*Q^T.
// ---------------------------------------------------------------------------
struct QTile {
  bf16x8 q[4][2];
  float li[4];
};

#define LOADQ(dst, rt_)                                                        \
  {                                                                            \
    _Pragma("unroll") for (int ifr = 0; ifr < 4; ifr++) {                      \
      _Pragma("unroll") for (int kk = 0; kk < 2; kk++)                         \
          dst.q[ifr][kk] = *(const bf16x8*)(Qh +                               \
              (size_t)((rt_)*64 + ifr * 16 + fr) * DP + kk * 32 + fg * 8);     \
      dst.li[ifr] = linv_h[(rt_)*64 + ifr * 16 + fr];                          \
    }                                                                          \
  }

#define COMPUTET(src, rt_)                                                     \
  {                                                                            \
    f32x4 tacc[2][4] = {};                                                     \
    _Pragma("unroll") for (int kk = 0; kk < 2; kk++)                           \
        _Pragma("unroll") for (int jm = 0; jm < 2; jm++)                       \
        _Pragma("unroll") for (int ifr = 0; ifr < 4; ifr++)                    \
            tacc[jm][ifr] = __builtin_amdgcn_mfma_f32_16x16x32_bf16(           \
                kf[jm][kk], src.q[ifr][kk], tacc[jm][ifr], 0, 0, 0);           \
    if ((rt_) == rt0) {                                                        \
      _Pragma("unroll") for (int jm = 0; jm < 2; jm++)                         \
          _Pragma("unroll") for (int ifr = 0; ifr < 4; ifr++)                  \
          _Pragma("unroll") for (int r = 0; r < 4; r++) {                      \
        int gi = (rt_)*64 + ifr * 16 + fr;                                     \
        int gj = ct * 32 + jm * 16 + fg * 4 + r;                               \
        if (gi >= gj)                                                          \
          s_acc[jm][r] += EXP2F(tacc[jm][ifr][r]) * src.li[ifr];               \
      }                                                                        \
    } else {                                                                   \
      _Pragma("unroll") for (int jm = 0; jm < 2; jm++)                         \
          _Pragma("unroll") for (int ifr = 0; ifr < 4; ifr++)                  \
          _Pragma("unroll") for (int r = 0; r < 4; r++)                        \
              s_acc[jm][r] += EXP2F(tacc[jm][ifr][r]) * src.li[ifr];           \
    }                                                                          \
  }

__global__ __launch_bounds__(256) void attn_aw(const u16* __restrict__ Qp,
                                               const u16* __restrict__ Kp,
                                               const float* __restrict__ linv_g,
                                               float* __restrict__ aw) {
  const int p = blockIdx.x, hk = blockIdx.y, b = blockIdx.z;
  const int t = threadIdx.x, w = t >> 6, lane = t & 63;
  const int fr = lane & 15, fg = lane >> 4;
  const int h = hk * 4 + w;

  const u16* Qh = Qp + (size_t)(b * HQ + h) * N_ * DP;
  const u16* Kh = Kp + (size_t)(b * HK + hk) * N_ * DP;
  const float* linv_h = linv_g + (size_t)(b * HQ + h) * N_;

  for (int half = 0; half < 2; ++half) {
    const int ct = half ? (63 - p) : p;
    const int rt0 = ct >> 1;

    bf16x8 kf[2][2];
#pragma unroll
    for (int jm = 0; jm < 2; jm++)
#pragma unroll
      for (int kk = 0; kk < 2; kk++)
        kf[jm][kk] = *(const bf16x8*)(Kh + (size_t)(ct * 32 + jm * 16 + fr) * DP +
                                      kk * 32 + fg * 8);

    float s_acc[2][4] = {};
    QTile qa, qb;
    LOADQ(qa, rt0);
    int rt = rt0;
    while (true) {
      if (rt + 1 <= 31) LOADQ(qb, rt + 1);
      COMPUTET(qa, rt);
      rt++;
      if (rt > 31) break;
      if (rt + 1 <= 31) LOADQ(qa, rt + 1);
      COMPUTET(qb, rt);
      rt++;
      if (rt > 31) break;
    }

#pragma unroll
    for (int jm = 0; jm < 2; jm++)
#pragma unroll
      for (int r = 0; r < 4; r++) {
        float v = s_acc[jm][r];
        v += __shfl_xor(v, 1);
        v += __shfl_xor(v, 2);
        v += __shfl_xor(v, 4);
        v += __shfl_xor(v, 8);
        if (fr == 0) {
          int gj = ct * 32 + jm * 16 + fg * 4 + r;
          aw[((size_t)b * N_ + gj) * HQ + h] = v * (1.0f / N_);
        }
      }
  }
}

// ---------------------------------------------------------------------------
// LayerNorm over EMBED, one block per row; bf16 output for the Wo GEMM.
// ---------------------------------------------------------------------------
__global__ __launch_bounds__(256) void ln_fwd(const float* __restrict__ AO,
                                              const float* __restrict__ gamma,
                                              const float* __restrict__ beta,
                                              u16* __restrict__ out) {
  const int row = blockIdx.x;
  const float* x = AO + (size_t)row * EMBED;
  const int t = threadIdx.x;
  float s = 0.f, s2 = 0.f;
  float v[4];
#pragma unroll
  for (int i = 0; i < 4; i++) {
    int c = t + 256 * i;
    v[i] = (c < EMBED) ? x[c] : 0.f;
    s += v[i];
    s2 += v[i] * v[i];
  }
#pragma unroll
  for (int m = 1; m <= 32; m <<= 1) {
    s += __shfl_xor(s, m);
    s2 += __shfl_xor(s2, m);
  }
  __shared__ float red[8];
  const int w = t >> 6, lane = t & 63;
  if (lane == 0) {
    red[w] = s;
    red[4 + w] = s2;
  }
  __syncthreads();
  s = red[0] + red[1] + red[2] + red[3];
  s2 = red[4] + red[5] + red[6] + red[7];
  const float mu = s * (1.0f / EMBED);
  const float var = s2 * (1.0f / EMBED) - mu * mu;
  const float rs = rsqrtf(var + 1e-5f);
#pragma unroll
  for (int i = 0; i < 4; i++) {
    int c = t + 256 * i;
    if (c < EMBED)
      out[(size_t)row * EMBED + c] = f2bf((v[i] - mu) * rs * gamma[c] + beta[c]);
  }
}

// ---------------------------------------------------------------------------
extern "C" void kernel_launch(void* const* d_in, const int* in_sizes, int n_in,
                              void* d_out, int out_size, void* d_ws,
                              size_t ws_size, hipStream_t stream) {
  (void)in_sizes; (void)n_in; (void)out_size; (void)ws_size;
  const float* query = (const float*)d_in[0];
  const float* key   = (const float*)d_in[1];
  const float* value = (const float*)d_in[2];
  const float* Wq    = (const float*)d_in[3];
  const float* Wk    = (const float*)d_in[4];
  const float* Wv    = (const float*)d_in[5];
  const float* Wo    = (const float*)d_in[6];
  const float* gamma = (const float*)d_in[7];
  const float* beta  = (const float*)d_in[8];

  float* out = (float*)d_out;                   // (b, n, EMBED) f32
  float* aw  = out + (size_t)B_ * N_ * EMBED;   // (b, s, HQ)   f32

  char* ws = (char*)d_ws;
  u16* Qp = (u16*)ws;        ws += (size_t)B_ * HQ * N_ * DP * 2;   // 8.39 MB
  u16* Kp = (u16*)ws;        ws += (size_t)B_ * HK * N_ * DP * 2;   // 2.10 MB
  u16* Vt = (u16*)ws;        ws += (size_t)B_ * HK * N_ * DP * 2;   // 2.10 MB
  float* linv = (float*)ws;  ws += (size_t)B_ * HQ * N_ * 4;        // 0.26 MB
  u16* Wqb = (u16*)ws;       ws += (size_t)SEG_WQ * 2;              // 1.61 MB
  u16* Wkb = (u16*)ws;       ws += (size_t)SEG_WK * 2;              // 0.40 MB
  u16* Wvb = (u16*)ws;       ws += (size_t)SEG_WK * 2;              // 0.40 MB
  u16* Wob = (u16*)ws;       ws += (size_t)SEG_WQ * 2;              // 1.61 MB
  char* region = ws;         // 22.02 MB region, two lifetimes:
  u16* qb = (u16*)region;                        // phase 1: qb/kb/vb
  u16* kb = qb + (size_t)SEG_IN;
  u16* vb = kb + (size_t)SEG_IN;
  float* AO = (float*)region;                    // phase 2: AO + LNo
  u16* LNo = (u16*)(region + (size_t)B_ * N_ * EMBED * 4);

  const size_t pad_bytes =
      ((size_t)B_ * HQ * N_ * DP + 2 * (size_t)B_ * HK * N_ * DP) * 2;
  (void)hipMemsetAsync(Qp, 0, pad_bytes, stream);  // zero d=56..63 pads

  dim3 blk(256);
  const int M = B_ * N_;  // 4096

  to_bf16<<<dim3(12712), blk, 0, stream>>>(query, key, value, Wq, Wk, Wv, Wo,
                                           qb, kb, vb, Wqb, Wkb, Wvb, Wob);

  proj_gemm<<<dim3(M / 128, 22), blk, 0, stream>>>(qb, kb, vb, Wqb, Wkb, Wvb,
                                                   Qp, Kp, Vt);

  attn_fwd<<<dim3(32, HK, B_), blk, 0, stream>>>(Qp, Kp, Vt, AO, linv);
  attn_aw<<<dim3(32, HK, B_), blk, 0, stream>>>(Qp, Kp, linv, aw);

  ln_fwd<<<dim3(M), blk, 0, stream>>>(AO, gamma, beta, LNo);
  gemm_wo<<<dim3(M / 128, 14), blk, 0, stream>>>(LNo, Wob, out);
}